// Round 6
// baseline (497.231 us; speedup 1.0000x reference)
//
#include <hip/hip_runtime.h>
#include <cstdint>

// GAT: N=50000 nodes, E=800000 edges, 128 -> 3 heads x 64, 2 layers, 10 classes
constexpr int KIN = 128;   // NDIM_IN
constexpr int HD  = 192;   // H * NDIM_OUT
constexpr int NC  = 10;    // CLASS_NUM
#define NEG_SLOPE 0.2f

typedef __attribute__((ext_vector_type(8))) short bf16x8;
typedef __attribute__((ext_vector_type(4))) float f32x4;

__device__ __forceinline__ float b2f(unsigned short u) {
    union { unsigned int i; float f; } x; x.i = ((unsigned int)u) << 16; return x.f;
}
__device__ __forceinline__ unsigned short f2b(float f) {
    union { float f; unsigned int i; } x; x.f = f;
    unsigned int r = x.i + 0x7FFFu + ((x.i >> 16) & 1u);   // RNE
    return (unsigned short)(r >> 16);
}
__device__ __forceinline__ float gload(const void* p, long i, int isbf) {
    return isbf ? b2f(((const unsigned short*)p)[i]) : ((const float*)p)[i];
}
__device__ __forceinline__ float lrelu(float v) { return v > 0.f ? v : NEG_SLOPE * v; }

// ================= fused prep: probe + zero(deg) + cvt(xb) + 4x pack =================
__global__ void k_prep(const void* __restrict__ nfeats, const void* __restrict__ W1,
                       const void* __restrict__ W2, const void* __restrict__ Wp,
                       unsigned short* __restrict__ xb, int* __restrict__ deg,
                       unsigned short* __restrict__ Bp1, unsigned short* __restrict__ Bp2,
                       unsigned short* __restrict__ BpPQ, int N, long nx,
                       int bZ, int bC, int* __restrict__ flag) {
    __shared__ int shIsb;
    if (threadIdx.x == 0) {
        const unsigned short* u = (const unsigned short*)W1;
        float mx = 0.f;
        for (int i = 0; i < 64; ++i) {
            float v = fabsf(b2f(u[i]));
            if (!(v < 1e30f)) v = 1e30f;
            mx = fmaxf(mx, v);
        }
        shIsb = (mx < 1e4f) ? 1 : 0;
        if (blockIdx.x == 0) *flag = shIsb;
    }
    __syncthreads();
    int isb = shIsb;
    int b = blockIdx.x, tid = threadIdx.x;
    if (b < bZ) { int i = b * 256 + tid; if (i < N) deg[i] = 0; return; }
    b -= bZ;
    if (b < bC) { long i = (long)b * 256 + tid; if (i < nx) xb[i] = f2b(gload(nfeats, i, isb)); return; }
    b -= bC;
    int t = b * 256 + tid;
    const int s1 = 12 * 4 * 512, s2 = s1 + 12 * 6 * 512, s3 = s2 + 6 * 512, s4 = s3 + 6 * 512;
    const void* W; unsigned short* Bp; int K, Creal, CT, KS; long rowOff; int tt;
    if (t < s1)      { W = W1; Bp = Bp1;            K = KIN; Creal = HD; CT = 12; KS = 4; rowOff = 0;  tt = t; }
    else if (t < s2) { W = W2; Bp = Bp2;            K = HD;  Creal = HD; CT = 12; KS = 6; rowOff = 0;  tt = t - s1; }
    else if (t < s3) { W = Wp; Bp = BpPQ;           K = HD;  Creal = NC; CT = 1;  KS = 6; rowOff = 0;  tt = t - s2; }
    else if (t < s4) { W = Wp; Bp = BpPQ + 6 * 512; K = HD;  Creal = NC; CT = 1;  KS = 6; rowOff = HD; tt = t - s3; }
    else return;
    int j = tt & 7, lane = (tt >> 3) & 63, ks = (tt >> 9) % KS, ct = tt / (KS * 512);
    int k = ks * 32 + ((lane >> 4) << 3) + j;
    int c = ct * 16 + (lane & 15);
    float v = 0.f;
    if (k < K && c < Creal) v = gload(W, (rowOff + k) * (long)Creal + c, isb);
    Bp[tt] = f2b(v);
}

// ---- MFMA GEMM + fused el/er epilogue. One wave = 16 rows x CT col-tiles.
template<int CT, int KS, int ELR>
__global__ void k_mm(const unsigned short* __restrict__ A, const unsigned short* __restrict__ Bp,
                     unsigned short* __restrict__ fb, const void* __restrict__ al,
                     const void* __restrict__ ar, float* __restrict__ el4,
                     float* __restrict__ er4, int M, int Cout, const int* __restrict__ flag) {
    int wid = threadIdx.x >> 6, lane = threadIdx.x & 63;
    int rt = blockIdx.x * 4 + wid;
    if (rt * 16 >= M) return;
    const int K = KS * 32;
    int mrow = rt * 16 + (lane & 15);
    int kq = (lane >> 4) << 3;
    f32x4 acc[CT];
#pragma unroll
    for (int ct = 0; ct < CT; ++ct) acc[ct] = (f32x4){0.f, 0.f, 0.f, 0.f};
    const unsigned short* arow = A + (long)mrow * K + kq;
    const bf16x8* bp = (const bf16x8*)Bp;
#pragma unroll
    for (int ks = 0; ks < KS; ++ks) {
        bf16x8 a = *(const bf16x8*)(arow + ks * 32);
#pragma unroll
        for (int ct = 0; ct < CT; ++ct) {
            bf16x8 b = bp[(ct * KS + ks) * 64 + lane];
            acc[ct] = __builtin_amdgcn_mfma_f32_16x16x32_bf16(a, b, acc[ct], 0, 0, 0);
        }
    }
    int quad = lane >> 4, c0 = lane & 15;
    int rbase = rt * 16 + quad * 4;
#pragma unroll
    for (int ct = 0; ct < CT; ++ct)
#pragma unroll
        for (int r = 0; r < 4; ++r)
            fb[(long)(rbase + r) * Cout + ct * 16 + c0] = f2b(acc[ct][r]);
    if (ELR) {
        int isb = *flag;
        float pl[3][4], pr[3][4];
#pragma unroll
        for (int h = 0; h < 3; ++h)
#pragma unroll
            for (int r = 0; r < 4; ++r) { pl[h][r] = 0.f; pr[h][r] = 0.f; }
#pragma unroll
        for (int ct = 0; ct < CT; ++ct) {
            int h = ct >> 2;
            float wl = gload(al, ct * 16 + c0, isb);
            float wr = gload(ar, ct * 16 + c0, isb);
#pragma unroll
            for (int r = 0; r < 4; ++r) {
                pl[h][r] += acc[ct][r] * wl;
                pr[h][r] += acc[ct][r] * wr;
            }
        }
#pragma unroll
        for (int d = 1; d < 16; d <<= 1)
#pragma unroll
            for (int h = 0; h < 3; ++h)
#pragma unroll
                for (int r = 0; r < 4; ++r) {
                    pl[h][r] += __shfl_xor(pl[h][r], d);
                    pr[h][r] += __shfl_xor(pr[h][r], d);
                }
        if (c0 == 0) {
#pragma unroll
            for (int r = 0; r < 4; ++r)
#pragma unroll
                for (int h = 0; h < 3; ++h) {
                    el4[(long)(rbase + r) * 4 + h] = pl[h][r];
                    er4[(long)(rbase + r) * 4 + h] = pr[h][r];
                }
        }
    }
}

// ---- fused P/Q gemm: PQ[M x 20] ----
__global__ void k_mmpq(const unsigned short* __restrict__ A, const unsigned short* __restrict__ Bp,
                       float* __restrict__ PQ, int M) {
    constexpr int CT = 2, KS = 6;
    int wid = threadIdx.x >> 6, lane = threadIdx.x & 63;
    int rt = blockIdx.x * 4 + wid;
    if (rt * 16 >= M) return;
    const int K = KS * 32;
    int mrow = rt * 16 + (lane & 15);
    int kq = (lane >> 4) << 3;
    f32x4 acc[CT];
#pragma unroll
    for (int ct = 0; ct < CT; ++ct) acc[ct] = (f32x4){0.f, 0.f, 0.f, 0.f};
    const unsigned short* arow = A + (long)mrow * K + kq;
    const bf16x8* bp = (const bf16x8*)Bp;
#pragma unroll
    for (int ks = 0; ks < KS; ++ks) {
        bf16x8 a = *(const bf16x8*)(arow + ks * 32);
#pragma unroll
        for (int ct = 0; ct < CT; ++ct) {
            bf16x8 b = bp[(ct * KS + ks) * 64 + lane];
            acc[ct] = __builtin_amdgcn_mfma_f32_16x16x32_bf16(a, b, acc[ct], 0, 0, 0);
        }
    }
    int quad = lane >> 4, c0 = lane & 15;
    int rbase = rt * 16 + quad * 4;
    if (c0 < NC) {
#pragma unroll
        for (int ct = 0; ct < CT; ++ct)
#pragma unroll
            for (int r = 0; r < 4; ++r)
                PQ[(long)(rbase + r) * (2 * NC) + ct * NC + c0] = acc[ct][r];
    }
}

// ---------------- CSR build ----------------
__global__ void k_hist(const int* __restrict__ dst, int E, int* __restrict__ deg) {
    int i = blockIdx.x * blockDim.x + threadIdx.x;
    if (i < E) atomicAdd(&deg[dst[i]], 1);
}

__global__ void k_scan1(const int* __restrict__ deg, int n, int* __restrict__ off,
                        int* __restrict__ bsum) {
    __shared__ int sh[1024];
    int tid = threadIdx.x, i = blockIdx.x * 1024 + tid;
    int v = (i < n) ? deg[i] : 0;
    sh[tid] = v;
    __syncthreads();
    for (int s = 1; s < 1024; s <<= 1) {
        int t = (tid >= s) ? sh[tid - s] : 0;
        __syncthreads();
        sh[tid] += t;
        __syncthreads();
    }
    if (i < n) off[i] = sh[tid] - v;
    if (tid == 1023) bsum[blockIdx.x] = sh[tid];
}

__global__ void k_scan2(int* __restrict__ bsum, int nb, int* __restrict__ off, int n) {
    int tid = threadIdx.x;
    int v = (tid < nb) ? bsum[tid] : 0;
    int incl = v;
    for (int s = 1; s < 64; s <<= 1) {
        int t = __shfl_up(incl, s);
        if (tid >= s) incl += t;
    }
    if (tid < nb) bsum[tid] = incl - v;
    if (tid == 63) off[n] = incl;
}

__global__ void k_scan3(int* __restrict__ off, const int* __restrict__ bsum, int n,
                        int* __restrict__ cur) {
    int i = blockIdx.x * 1024 + threadIdx.x;
    if (i < n) {
        int v = off[i] + bsum[blockIdx.x];
        off[i] = v;
        cur[i] = v;
    }
}

__global__ void k_fill(const int* __restrict__ src, const int* __restrict__ dst, int E,
                       int* __restrict__ cur, int* __restrict__ csr) {
    int i = blockIdx.x * blockDim.x + threadIdx.x;
    if (i < E) {
        int p = atomicAdd(&cur[dst[i]], 1);
        csr[p] = src[i];
    }
}

// ---- softmax + aggregation, one wave per node; packed-uint bf16 feature gather ----
// Lane l handles cols {2l, 2l+1} (head = l<32 ? 0 : 1); lanes 0-31 also {128+2l, 129+2l} (head 2).
__global__ void __launch_bounds__(256, 8)
k_agg(const unsigned int* __restrict__ fbu, const float4* __restrict__ el4,
      const float* __restrict__ er4, const int* __restrict__ off,
      const int* __restrict__ csr, const void* __restrict__ bias,
      unsigned int* __restrict__ outu, int Nn, const int* __restrict__ flag) {
    int lane = threadIdx.x & 63;
    int n = blockIdx.x * 4 + (threadIdx.x >> 6);
    if (n >= Nn) return;
    int isb = *flag;
    int s0 = off[n], s1 = off[n + 1];
    int deg = s1 - s0;
    float er0 = er4[n * 4 + 0], er1 = er4[n * 4 + 1], er2 = er4[n * 4 + 2];
    bool lo32 = lane < 32;
    float aa0 = 0.f, aa1 = 0.f, ab0 = 0.f, ab1 = 0.f;

    if (deg > 0 && deg <= 64) {
        int e = s0 + lane;
        bool on = e < s1;
        int sIdx = on ? csr[e] : 0;
        float4 el = el4[sIdx];
        float t0 = on ? lrelu(el.x + er0) : -1e30f;
        float t1 = on ? lrelu(el.y + er1) : -1e30f;
        float t2 = on ? lrelu(el.z + er2) : -1e30f;
        float m0 = t0, m1 = t1, m2 = t2;
        for (int d = 1; d < 64; d <<= 1) {
            m0 = fmaxf(m0, __shfl_xor(m0, d));
            m1 = fmaxf(m1, __shfl_xor(m1, d));
            m2 = fmaxf(m2, __shfl_xor(m2, d));
        }
        float w0 = on ? __expf(t0 - m0) : 0.f;
        float w1 = on ? __expf(t1 - m1) : 0.f;
        float w2 = on ? __expf(t2 - m2) : 0.f;
        float d0 = w0, d1 = w1, d2 = w2;
        for (int d = 1; d < 64; d <<= 1) {
            d0 += __shfl_xor(d0, d);
            d1 += __shfl_xor(d1, d);
            d2 += __shfl_xor(d2, d);
        }
        w0 *= 1.f / d0; w1 *= 1.f / d1; w2 *= 1.f / d2;
#pragma unroll 8
        for (int j = 0; j < deg; ++j) {
            int s = __shfl(sIdx, j);
            float u0 = __shfl(w0, j), u1 = __shfl(w1, j), u2 = __shfl(w2, j);
            float wa = lo32 ? u0 : u1;
            const unsigned int* fr = fbu + (long)s * 96;
            unsigned int ua = fr[lane];
            aa0 += wa * b2f((unsigned short)ua);
            aa1 += wa * b2f((unsigned short)(ua >> 16));
            if (lo32) {
                unsigned int ub = fr[64 + lane];
                ab0 += u2 * b2f((unsigned short)ub);
                ab1 += u2 * b2f((unsigned short)(ub >> 16));
            }
        }
    } else if (deg > 64) {
        float m0 = -1e30f, m1 = -1e30f, m2 = -1e30f;
        for (int e = s0 + lane; e < s1; e += 64) {
            float4 el = el4[csr[e]];
            m0 = fmaxf(m0, lrelu(el.x + er0));
            m1 = fmaxf(m1, lrelu(el.y + er1));
            m2 = fmaxf(m2, lrelu(el.z + er2));
        }
        for (int d = 1; d < 64; d <<= 1) {
            m0 = fmaxf(m0, __shfl_xor(m0, d));
            m1 = fmaxf(m1, __shfl_xor(m1, d));
            m2 = fmaxf(m2, __shfl_xor(m2, d));
        }
        float d0 = 0.f, d1 = 0.f, d2 = 0.f;
        for (int e = s0 + lane; e < s1; e += 64) {
            float4 el = el4[csr[e]];
            d0 += __expf(lrelu(el.x + er0) - m0);
            d1 += __expf(lrelu(el.y + er1) - m1);
            d2 += __expf(lrelu(el.z + er2) - m2);
        }
        for (int d = 1; d < 64; d <<= 1) {
            d0 += __shfl_xor(d0, d);
            d1 += __shfl_xor(d1, d);
            d2 += __shfl_xor(d2, d);
        }
        float id0 = 1.f / d0, id1 = 1.f / d1, id2 = 1.f / d2;
        for (int e = s0; e < s1; ++e) {
            int s = csr[e];
            float4 el = el4[s];
            float u0 = __expf(lrelu(el.x + er0) - m0) * id0;
            float u1 = __expf(lrelu(el.y + er1) - m1) * id1;
            float u2 = __expf(lrelu(el.z + er2) - m2) * id2;
            float wa = lo32 ? u0 : u1;
            const unsigned int* fr = fbu + (long)s * 96;
            unsigned int ua = fr[lane];
            aa0 += wa * b2f((unsigned short)ua);
            aa1 += wa * b2f((unsigned short)(ua >> 16));
            if (lo32) {
                unsigned int ub = fr[64 + lane];
                ab0 += u2 * b2f((unsigned short)ub);
                ab1 += u2 * b2f((unsigned short)(ub >> 16));
            }
        }
    }
    int ca = 2 * lane;
    aa0 = fmaxf(aa0 + gload(bias, ca,     isb), 0.f);
    aa1 = fmaxf(aa1 + gload(bias, ca + 1, isb), 0.f);
    unsigned int* orow = outu + (long)n * 96;
    orow[lane] = (unsigned)f2b(aa0) | ((unsigned)f2b(aa1) << 16);
    if (lo32) {
        int cb = 128 + 2 * lane;
        ab0 = fmaxf(ab0 + gload(bias, cb,     isb), 0.f);
        ab1 = fmaxf(ab1 + gload(bias, cb + 1, isb), 0.f);
        orow[64 + lane] = (unsigned)f2b(ab0) | ((unsigned)f2b(ab1) << 16);
    }
}

// ---- per-edge score with LDS-staged coalesced writes ----
__global__ void k_score(const int* __restrict__ src, const int* __restrict__ dst,
                        const float* __restrict__ PQ, const void* __restrict__ bp,
                        void* __restrict__ out, int E, const int* __restrict__ flag) {
    __shared__ float sh[256 * NC];
    int tid = threadIdx.x;
    int e0 = blockIdx.x * 256;
    int e = e0 + tid;
    int isb = *flag;
    float v[NC];
    if (e < E) {
        const float* pr = PQ + (long)src[e] * (2 * NC);
        const float* qr = PQ + (long)dst[e] * (2 * NC) + NC;
#pragma unroll
        for (int c = 0; c < NC; ++c) v[c] = pr[c] + qr[c] + gload(bp, c, isb);
    }
    int nE = min(256, E - e0);
    if (isb) {
        unsigned int* shu = (unsigned int*)sh;
        if (e < E) {
#pragma unroll
            for (int c = 0; c < NC / 2; ++c)
                shu[tid * (NC / 2) + c] =
                    (unsigned)f2b(v[2 * c]) | ((unsigned)f2b(v[2 * c + 1]) << 16);
        }
        __syncthreads();
        int nU = nE * (NC / 2);
        unsigned int* ob = (unsigned int*)((unsigned short*)out + (long)e0 * NC);
        int nU4 = nU >> 2;
        uint4* ob4 = (uint4*)ob;
        const uint4* sb4 = (const uint4*)shu;
        for (int u = tid; u < nU4; u += 256) ob4[u] = sb4[u];
        for (int w = (nU4 << 2) + tid; w < nU; w += 256) ob[w] = shu[w];
    } else {
        if (e < E) {
#pragma unroll
            for (int c = 0; c < NC; ++c) sh[tid * NC + c] = v[c];
        }
        __syncthreads();
        int nU = nE * NC;
        float* ob = (float*)out + (long)e0 * NC;
        int nU4 = nU >> 2;
        float4* ob4 = (float4*)ob;
        const float4* sb4 = (const float4*)sh;
        for (int u = tid; u < nU4; u += 256) ob4[u] = sb4[u];
        for (int w = (nU4 << 2) + tid; w < nU; w += 256) ob[w] = sh[w];
    }
}

extern "C" void kernel_launch(void* const* d_in, const int* in_sizes, int n_in,
                              void* d_out, int out_size, void* d_ws, size_t ws_size,
                              hipStream_t stream) {
    const int* src = (const int*)d_in[0];
    const int* dst = (const int*)d_in[1];
    const void* nfeats = d_in[2];
    // d_in[3] = efeats, unused
    const void* W1  = d_in[4];
    const void* al1 = d_in[5];
    const void* ar1 = d_in[6];
    const void* b1  = d_in[7];
    const void* W2  = d_in[8];
    const void* al2 = d_in[9];
    const void* ar2 = d_in[10];
    const void* b2  = d_in[11];
    const void* Wp  = d_in[12];
    const void* bp  = d_in[13];

    const int E = in_sizes[0];
    const int N = in_sizes[2] / KIN;

    // workspace layout (256B aligned)
    size_t o = 0;
    auto alloc = [&](size_t bytes) { size_t r = o; o = (o + bytes + 255) & ~(size_t)255; return r; };
    char* ws = (char*)d_ws;
    int*   flag = (int*)  (ws + alloc(4));
    int*   deg  = (int*)  (ws + alloc((size_t)N * 4));
    int*   off  = (int*)  (ws + alloc((size_t)(N + 1) * 4));
    int*   cur  = (int*)  (ws + alloc((size_t)N * 4));
    int*   bsum = (int*)  (ws + alloc(64 * 4));
    int*   csr  = (int*)  (ws + alloc((size_t)E * 4));
    unsigned short* xb  = (unsigned short*)(ws + alloc((size_t)N * KIN * 2));
    unsigned short* fb  = (unsigned short*)(ws + alloc((size_t)N * HD * 2));
    unsigned short* hb  = (unsigned short*)(ws + alloc((size_t)N * HD * 2));
    unsigned short* Bp1 = (unsigned short*)(ws + alloc((size_t)12 * 4 * 512 * 2));
    unsigned short* Bp2 = (unsigned short*)(ws + alloc((size_t)12 * 6 * 512 * 2));
    unsigned short* BpPQ= (unsigned short*)(ws + alloc((size_t)2 * 6 * 512 * 2));
    float* el4  = (float*)(ws + alloc((size_t)N * 16));
    float* er4  = (float*)(ws + alloc((size_t)N * 16));
    float* PQ   = (float*)(ws + alloc((size_t)N * 2 * NC * 4));
    (void)ws_size; (void)n_in; (void)out_size;

    const int TB = 256;
    long nx = (long)N * KIN;
    int gE   = (E + TB - 1) / TB;
    int gAgg = (N + 3) / 4;
    int rowTiles = (N + 15) / 16;
    int gMM  = (rowTiles + 3) / 4;
    int nb   = (N + 1023) / 1024;

    // fused prep: probe + zero(deg) + cvt(xb) + all B-packs
    int bZ = (N + TB - 1) / TB;
    int bC = (int)((nx + TB - 1) / TB);
    int bP = (12 * 4 * 512 + 12 * 6 * 512 + 2 * 6 * 512 + TB - 1) / TB;
    k_prep<<<bZ + bC + bP, TB, 0, stream>>>(nfeats, W1, W2, Wp, xb, deg,
                                            Bp1, Bp2, BpPQ, N, nx, bZ, bC, flag);

    // CSR build (dst-indexed), hierarchical scan
    k_hist<<<gE, TB, 0, stream>>>(dst, E, deg);
    k_scan1<<<nb, 1024, 0, stream>>>(deg, N, off, bsum);
    k_scan2<<<1, 64, 0, stream>>>(bsum, nb, off, N);
    k_scan3<<<nb, 1024, 0, stream>>>(off, bsum, N, cur);
    k_fill<<<gE, TB, 0, stream>>>(src, dst, E, cur, csr);

    // layer 1: fused gemm+el/er, then softmax-aggregate
    k_mm<12, 4, 1><<<gMM, TB, 0, stream>>>(xb, Bp1, fb, al1, ar1, el4, er4, N, HD, flag);
    k_agg<<<gAgg, TB, 0, stream>>>((const unsigned int*)fb, (const float4*)el4, er4,
                                   off, csr, b1, (unsigned int*)hb, N, flag);

    // layer 2
    k_mm<12, 6, 1><<<gMM, TB, 0, stream>>>(hb, Bp2, fb, al2, ar2, el4, er4, N, HD, flag);
    k_agg<<<gAgg, TB, 0, stream>>>((const unsigned int*)fb, (const float4*)el4, er4,
                                   off, csr, b2, (unsigned int*)hb, N, flag);

    // predictor
    k_mmpq<<<gMM, TB, 0, stream>>>(hb, BpPQ, PQ, N);
    k_score<<<gE, TB, 0, stream>>>(src, dst, PQ, bp, d_out, E, flag);
}

// Round 7
// 441.305 us; speedup vs baseline: 1.1267x; 1.1267x over previous
//
#include <hip/hip_runtime.h>
#include <cstdint>

// GAT: N=50000 nodes, E=800000 edges, 128 -> 3 heads x 64, 2 layers, 10 classes
constexpr int KIN = 128;   // NDIM_IN
constexpr int HD  = 192;   // H * NDIM_OUT
constexpr int NC  = 10;    // CLASS_NUM
#define NEG_SLOPE 0.2f

typedef __attribute__((ext_vector_type(8))) short bf16x8;
typedef __attribute__((ext_vector_type(4))) float f32x4;

__device__ __forceinline__ float b2f(unsigned short u) {
    union { unsigned int i; float f; } x; x.i = ((unsigned int)u) << 16; return x.f;
}
__device__ __forceinline__ float b2f_lo(unsigned int u) {
    union { unsigned int i; float f; } x; x.i = u << 16; return x.f;
}
__device__ __forceinline__ float b2f_hi(unsigned int u) {
    union { unsigned int i; float f; } x; x.i = u & 0xffff0000u; return x.f;
}
__device__ __forceinline__ unsigned short f2b(float f) {
    union { float f; unsigned int i; } x; x.f = f;
    unsigned int r = x.i + 0x7FFFu + ((x.i >> 16) & 1u);   // RNE
    return (unsigned short)(r >> 16);
}
__device__ __forceinline__ float gload(const void* p, long i, int isbf) {
    return isbf ? b2f(((const unsigned short*)p)[i]) : ((const float*)p)[i];
}
__device__ __forceinline__ float lrelu(float v) { return v > 0.f ? v : NEG_SLOPE * v; }

// ================= fused prep: probe + zero(deg) + cvt(xb) + 4x pack =================
__global__ void k_prep(const void* __restrict__ nfeats, const void* __restrict__ W1,
                       const void* __restrict__ W2, const void* __restrict__ Wp,
                       unsigned short* __restrict__ xb, int* __restrict__ deg,
                       unsigned short* __restrict__ Bp1, unsigned short* __restrict__ Bp2,
                       unsigned short* __restrict__ BpPQ, int N, long nx,
                       int bZ, int bC, int* __restrict__ flag) {
    __shared__ int shIsb;
    if (threadIdx.x == 0) {
        const unsigned short* u = (const unsigned short*)W1;
        float mx = 0.f;
        for (int i = 0; i < 64; ++i) {
            float v = fabsf(b2f(u[i]));
            if (!(v < 1e30f)) v = 1e30f;
            mx = fmaxf(mx, v);
        }
        shIsb = (mx < 1e4f) ? 1 : 0;
        if (blockIdx.x == 0) *flag = shIsb;
    }
    __syncthreads();
    int isb = shIsb;
    int b = blockIdx.x, tid = threadIdx.x;
    if (b < bZ) { int i = b * 256 + tid; if (i < N) deg[i] = 0; return; }
    b -= bZ;
    if (b < bC) {
        if (isb) return;                    // bf16 input: k_mm reads nfeats directly
        long i = (long)b * 256 + tid;
        if (i < nx) xb[i] = f2b(gload(nfeats, i, isb));
        return;
    }
    b -= bC;
    int t = b * 256 + tid;
    const int s1 = 12 * 4 * 512, s2 = s1 + 12 * 6 * 512, s3 = s2 + 6 * 512, s4 = s3 + 6 * 512;
    const void* W; unsigned short* Bp; int K, Creal, KS; long rowOff; int tt;
    if (t < s1)      { W = W1; Bp = Bp1;            K = KIN; Creal = HD; KS = 4; rowOff = 0;  tt = t; }
    else if (t < s2) { W = W2; Bp = Bp2;            K = HD;  Creal = HD; KS = 6; rowOff = 0;  tt = t - s1; }
    else if (t < s3) { W = Wp; Bp = BpPQ;           K = HD;  Creal = NC; KS = 6; rowOff = 0;  tt = t - s2; }
    else if (t < s4) { W = Wp; Bp = BpPQ + 6 * 512; K = HD;  Creal = NC; KS = 6; rowOff = HD; tt = t - s3; }
    else return;
    int j = tt & 7, lane = (tt >> 3) & 63, ks = (tt >> 9) % KS, ct = tt / (KS * 512);
    int k = ks * 32 + ((lane >> 4) << 3) + j;
    int c = ct * 16 + (lane & 15);
    float v = 0.f;
    if (k < K && c < Creal) v = gload(W, (rowOff + k) * (long)Creal + c, isb);
    Bp[tt] = f2b(v);
}

// ---- MFMA GEMM + fused el/er epilogue. One wave = 16 rows x CT col-tiles.
// A = flag ? Ain (harness bf16) : xb (staged); pass same pointer twice for internal inputs.
template<int CT, int KS, int ELR>
__global__ void k_mm(const void* __restrict__ Ain, const unsigned short* __restrict__ xbA,
                     const unsigned short* __restrict__ Bp,
                     unsigned short* __restrict__ fb, const void* __restrict__ al,
                     const void* __restrict__ ar, float* __restrict__ el4,
                     float* __restrict__ er4, int M, int Cout, const int* __restrict__ flag) {
    int wid = threadIdx.x >> 6, lane = threadIdx.x & 63;
    int rt = blockIdx.x * 4 + wid;
    if (rt * 16 >= M) return;
    int isb = *flag;
    const unsigned short* A = isb ? (const unsigned short*)Ain : xbA;
    const int K = KS * 32;
    int mrow = rt * 16 + (lane & 15);
    int kq = (lane >> 4) << 3;
    f32x4 acc[CT];
#pragma unroll
    for (int ct = 0; ct < CT; ++ct) acc[ct] = (f32x4){0.f, 0.f, 0.f, 0.f};
    const unsigned short* arow = A + (long)mrow * K + kq;
    const bf16x8* bp = (const bf16x8*)Bp;
#pragma unroll
    for (int ks = 0; ks < KS; ++ks) {
        bf16x8 a = *(const bf16x8*)(arow + ks * 32);
#pragma unroll
        for (int ct = 0; ct < CT; ++ct) {
            bf16x8 b = bp[(ct * KS + ks) * 64 + lane];
            acc[ct] = __builtin_amdgcn_mfma_f32_16x16x32_bf16(a, b, acc[ct], 0, 0, 0);
        }
    }
    int quad = lane >> 4, c0 = lane & 15;
    int rbase = rt * 16 + quad * 4;
#pragma unroll
    for (int ct = 0; ct < CT; ++ct)
#pragma unroll
        for (int r = 0; r < 4; ++r)
            fb[(long)(rbase + r) * Cout + ct * 16 + c0] = f2b(acc[ct][r]);
    if (ELR) {
        float pl[3][4], pr[3][4];
#pragma unroll
        for (int h = 0; h < 3; ++h)
#pragma unroll
            for (int r = 0; r < 4; ++r) { pl[h][r] = 0.f; pr[h][r] = 0.f; }
#pragma unroll
        for (int ct = 0; ct < CT; ++ct) {
            int h = ct >> 2;
            float wl = gload(al, ct * 16 + c0, isb);
            float wr = gload(ar, ct * 16 + c0, isb);
#pragma unroll
            for (int r = 0; r < 4; ++r) {
                pl[h][r] += acc[ct][r] * wl;
                pr[h][r] += acc[ct][r] * wr;
            }
        }
#pragma unroll
        for (int d = 1; d < 16; d <<= 1)
#pragma unroll
            for (int h = 0; h < 3; ++h)
#pragma unroll
                for (int r = 0; r < 4; ++r) {
                    pl[h][r] += __shfl_xor(pl[h][r], d);
                    pr[h][r] += __shfl_xor(pr[h][r], d);
                }
        if (c0 == 0) {
#pragma unroll
            for (int r = 0; r < 4; ++r)
#pragma unroll
                for (int h = 0; h < 3; ++h) {
                    el4[(long)(rbase + r) * 4 + h] = pl[h][r];
                    er4[(long)(rbase + r) * 4 + h] = pr[h][r];
                }
        }
    }
}

// ---- fused P/Q gemm: PQ[M x 20] ----
__global__ void k_mmpq(const unsigned short* __restrict__ A, const unsigned short* __restrict__ Bp,
                       float* __restrict__ PQ, int M) {
    constexpr int CT = 2, KS = 6;
    int wid = threadIdx.x >> 6, lane = threadIdx.x & 63;
    int rt = blockIdx.x * 4 + wid;
    if (rt * 16 >= M) return;
    const int K = KS * 32;
    int mrow = rt * 16 + (lane & 15);
    int kq = (lane >> 4) << 3;
    f32x4 acc[CT];
#pragma unroll
    for (int ct = 0; ct < CT; ++ct) acc[ct] = (f32x4){0.f, 0.f, 0.f, 0.f};
    const unsigned short* arow = A + (long)mrow * K + kq;
    const bf16x8* bp = (const bf16x8*)Bp;
#pragma unroll
    for (int ks = 0; ks < KS; ++ks) {
        bf16x8 a = *(const bf16x8*)(arow + ks * 32);
#pragma unroll
        for (int ct = 0; ct < CT; ++ct) {
            bf16x8 b = bp[(ct * KS + ks) * 64 + lane];
            acc[ct] = __builtin_amdgcn_mfma_f32_16x16x32_bf16(a, b, acc[ct], 0, 0, 0);
        }
    }
    int quad = lane >> 4, c0 = lane & 15;
    int rbase = rt * 16 + quad * 4;
    if (c0 < NC) {
#pragma unroll
        for (int ct = 0; ct < CT; ++ct)
#pragma unroll
            for (int r = 0; r < 4; ++r)
                PQ[(long)(rbase + r) * (2 * NC) + ct * NC + c0] = acc[ct][r];
    }
}

// ---------------- CSR build ----------------
__global__ void k_hist(const int* __restrict__ dst, int E, int* __restrict__ deg) {
    int i = blockIdx.x * blockDim.x + threadIdx.x;
    if (i < E) atomicAdd(&deg[dst[i]], 1);
}

__global__ void k_scan1(const int* __restrict__ deg, int n, int* __restrict__ off,
                        int* __restrict__ bsum) {
    __shared__ int sh[1024];
    int tid = threadIdx.x, i = blockIdx.x * 1024 + tid;
    int v = (i < n) ? deg[i] : 0;
    sh[tid] = v;
    __syncthreads();
    for (int s = 1; s < 1024; s <<= 1) {
        int t = (tid >= s) ? sh[tid - s] : 0;
        __syncthreads();
        sh[tid] += t;
        __syncthreads();
    }
    if (i < n) off[i] = sh[tid] - v;
    if (tid == 1023) bsum[blockIdx.x] = sh[tid];
}

__global__ void k_scan2(int* __restrict__ bsum, int nb, int* __restrict__ off, int n) {
    int tid = threadIdx.x;
    int v = (tid < nb) ? bsum[tid] : 0;
    int incl = v;
    for (int s = 1; s < 64; s <<= 1) {
        int t = __shfl_up(incl, s);
        if (tid >= s) incl += t;
    }
    if (tid < nb) bsum[tid] = incl - v;
    if (tid == 63) off[n] = incl;
}

__global__ void k_scan3(int* __restrict__ off, const int* __restrict__ bsum, int n,
                        int* __restrict__ cur) {
    int i = blockIdx.x * 1024 + threadIdx.x;
    if (i < n) {
        int v = off[i] + bsum[blockIdx.x];
        off[i] = v;
        cur[i] = v;
    }
}

__global__ void k_fill(const int* __restrict__ src, const int* __restrict__ dst, int E,
                       int* __restrict__ cur, int* __restrict__ csr) {
    int i = blockIdx.x * blockDim.x + threadIdx.x;
    if (i < E) {
        int p = atomicAdd(&cur[dst[i]], 1);
        csr[p] = src[i];
    }
}

// ---- softmax + aggregation, one wave per node ----
// Weights+idx staged in LDS by the full wave; gather loop runs on lanes 0-47,
// lane l owning cols [4l, 4l+4) -> one uint2 (dwordx2) load per edge.
__global__ void k_agg(const unsigned int* __restrict__ fbu, const float4* __restrict__ el4,
                      const float* __restrict__ er4, const int* __restrict__ off,
                      const int* __restrict__ csr, const void* __restrict__ bias,
                      unsigned int* __restrict__ outu, int Nn, const int* __restrict__ flag) {
    __shared__ float4 shW[4][64];
    int lane = threadIdx.x & 63;
    int wv = threadIdx.x >> 6;
    int n = blockIdx.x * 4 + wv;
    if (n >= Nn) return;
    int isb = *flag;
    int s0 = off[n], s1 = off[n + 1];
    int deg = s1 - s0;
    float er0 = er4[n * 4 + 0], er1 = er4[n * 4 + 1], er2 = er4[n * 4 + 2];
    int hsel = lane >> 4;                       // 0,1,2 for lanes<48
    float a0 = 0.f, a1 = 0.f, a2 = 0.f, a3 = 0.f;

    if (deg <= 64) {
        bool on = lane < deg;
        int sIdx = on ? csr[s0 + lane] : 0;
        float4 el = el4[sIdx];
        float t0 = on ? lrelu(el.x + er0) : -1e30f;
        float t1 = on ? lrelu(el.y + er1) : -1e30f;
        float t2 = on ? lrelu(el.z + er2) : -1e30f;
        float m0 = t0, m1 = t1, m2 = t2;
        for (int d = 1; d < 64; d <<= 1) {
            m0 = fmaxf(m0, __shfl_xor(m0, d));
            m1 = fmaxf(m1, __shfl_xor(m1, d));
            m2 = fmaxf(m2, __shfl_xor(m2, d));
        }
        float w0 = on ? __expf(t0 - m0) : 0.f;
        float w1 = on ? __expf(t1 - m1) : 0.f;
        float w2 = on ? __expf(t2 - m2) : 0.f;
        float d0 = w0, d1 = w1, d2 = w2;
        for (int d = 1; d < 64; d <<= 1) {
            d0 += __shfl_xor(d0, d);
            d1 += __shfl_xor(d1, d);
            d2 += __shfl_xor(d2, d);
        }
        w0 *= 1.f / d0; w1 *= 1.f / d1; w2 *= 1.f / d2;
        shW[wv][lane] = make_float4(__int_as_float(sIdx), w0, w1, w2);
        if (lane < 48) {
            const float4* wr = shW[wv];
            long lb = 2 * lane;
            int j = 0;
            for (; j + 4 <= deg; j += 4) {
                float4 r0 = wr[j], r1 = wr[j + 1], r2 = wr[j + 2], r3 = wr[j + 3];
                uint2 u0 = *(const uint2*)(fbu + (long)__float_as_int(r0.x) * 96 + lb);
                uint2 u1 = *(const uint2*)(fbu + (long)__float_as_int(r1.x) * 96 + lb);
                uint2 u2 = *(const uint2*)(fbu + (long)__float_as_int(r2.x) * 96 + lb);
                uint2 u3 = *(const uint2*)(fbu + (long)__float_as_int(r3.x) * 96 + lb);
                float q0 = hsel == 0 ? r0.y : (hsel == 1 ? r0.z : r0.w);
                float q1 = hsel == 0 ? r1.y : (hsel == 1 ? r1.z : r1.w);
                float q2 = hsel == 0 ? r2.y : (hsel == 1 ? r2.z : r2.w);
                float q3 = hsel == 0 ? r3.y : (hsel == 1 ? r3.z : r3.w);
                a0 += q0 * b2f_lo(u0.x); a1 += q0 * b2f_hi(u0.x);
                a2 += q0 * b2f_lo(u0.y); a3 += q0 * b2f_hi(u0.y);
                a0 += q1 * b2f_lo(u1.x); a1 += q1 * b2f_hi(u1.x);
                a2 += q1 * b2f_lo(u1.y); a3 += q1 * b2f_hi(u1.y);
                a0 += q2 * b2f_lo(u2.x); a1 += q2 * b2f_hi(u2.x);
                a2 += q2 * b2f_lo(u2.y); a3 += q2 * b2f_hi(u2.y);
                a0 += q3 * b2f_lo(u3.x); a1 += q3 * b2f_hi(u3.x);
                a2 += q3 * b2f_lo(u3.y); a3 += q3 * b2f_hi(u3.y);
            }
            for (; j < deg; ++j) {
                float4 r0 = wr[j];
                uint2 u0 = *(const uint2*)(fbu + (long)__float_as_int(r0.x) * 96 + lb);
                float q0 = hsel == 0 ? r0.y : (hsel == 1 ? r0.z : r0.w);
                a0 += q0 * b2f_lo(u0.x); a1 += q0 * b2f_hi(u0.x);
                a2 += q0 * b2f_lo(u0.y); a3 += q0 * b2f_hi(u0.y);
            }
        }
    } else {
        float m0 = -1e30f, m1 = -1e30f, m2 = -1e30f;
        for (int e = s0 + lane; e < s1; e += 64) {
            float4 el = el4[csr[e]];
            m0 = fmaxf(m0, lrelu(el.x + er0));
            m1 = fmaxf(m1, lrelu(el.y + er1));
            m2 = fmaxf(m2, lrelu(el.z + er2));
        }
        for (int d = 1; d < 64; d <<= 1) {
            m0 = fmaxf(m0, __shfl_xor(m0, d));
            m1 = fmaxf(m1, __shfl_xor(m1, d));
            m2 = fmaxf(m2, __shfl_xor(m2, d));
        }
        float d0 = 0.f, d1 = 0.f, d2 = 0.f;
        for (int e = s0 + lane; e < s1; e += 64) {
            float4 el = el4[csr[e]];
            d0 += __expf(lrelu(el.x + er0) - m0);
            d1 += __expf(lrelu(el.y + er1) - m1);
            d2 += __expf(lrelu(el.z + er2) - m2);
        }
        for (int d = 1; d < 64; d <<= 1) {
            d0 += __shfl_xor(d0, d);
            d1 += __shfl_xor(d1, d);
            d2 += __shfl_xor(d2, d);
        }
        if (lane < 48) {
            float mh  = hsel == 0 ? m0 : (hsel == 1 ? m1 : m2);
            float dh  = hsel == 0 ? d0 : (hsel == 1 ? d1 : d2);
            float erh = hsel == 0 ? er0 : (hsel == 1 ? er1 : er2);
            float idh = 1.f / dh;
            long lb = 2 * lane;
            for (int e = s0; e < s1; ++e) {
                int s = csr[e];
                float4 el = el4[s];
                float eh = hsel == 0 ? el.x : (hsel == 1 ? el.y : el.z);
                float w = __expf(lrelu(eh + erh) - mh) * idh;
                uint2 u = *(const uint2*)(fbu + (long)s * 96 + lb);
                a0 += w * b2f_lo(u.x); a1 += w * b2f_hi(u.x);
                a2 += w * b2f_lo(u.y); a3 += w * b2f_hi(u.y);
            }
        }
    }
    if (lane < 48) {
        int c = 4 * lane;
        a0 = fmaxf(a0 + gload(bias, c,     isb), 0.f);
        a1 = fmaxf(a1 + gload(bias, c + 1, isb), 0.f);
        a2 = fmaxf(a2 + gload(bias, c + 2, isb), 0.f);
        a3 = fmaxf(a3 + gload(bias, c + 3, isb), 0.f);
        uint2 o;
        o.x = (unsigned)f2b(a0) | ((unsigned)f2b(a1) << 16);
        o.y = (unsigned)f2b(a2) | ((unsigned)f2b(a3) << 16);
        *(uint2*)(outu + (long)n * 96 + 2 * lane) = o;
    }
}

// ---- per-edge score with LDS-staged coalesced writes ----
__global__ void k_score(const int* __restrict__ src, const int* __restrict__ dst,
                        const float* __restrict__ PQ, const void* __restrict__ bp,
                        void* __restrict__ out, int E, const int* __restrict__ flag) {
    __shared__ float sh[256 * NC];
    int tid = threadIdx.x;
    int e0 = blockIdx.x * 256;
    int e = e0 + tid;
    int isb = *flag;
    float v[NC];
    if (e < E) {
        const float* pr = PQ + (long)src[e] * (2 * NC);
        const float* qr = PQ + (long)dst[e] * (2 * NC) + NC;
#pragma unroll
        for (int c = 0; c < NC; ++c) v[c] = pr[c] + qr[c] + gload(bp, c, isb);
    }
    int nE = min(256, E - e0);
    if (isb) {
        unsigned int* shu = (unsigned int*)sh;
        if (e < E) {
#pragma unroll
            for (int c = 0; c < NC / 2; ++c)
                shu[tid * (NC / 2) + c] =
                    (unsigned)f2b(v[2 * c]) | ((unsigned)f2b(v[2 * c + 1]) << 16);
        }
        __syncthreads();
        int nU = nE * (NC / 2);
        unsigned int* ob = (unsigned int*)((unsigned short*)out + (long)e0 * NC);
        int nU4 = nU >> 2;
        uint4* ob4 = (uint4*)ob;
        const uint4* sb4 = (const uint4*)shu;
        for (int u = tid; u < nU4; u += 256) ob4[u] = sb4[u];
        for (int w = (nU4 << 2) + tid; w < nU; w += 256) ob[w] = shu[w];
    } else {
        if (e < E) {
#pragma unroll
            for (int c = 0; c < NC; ++c) sh[tid * NC + c] = v[c];
        }
        __syncthreads();
        int nU = nE * NC;
        float* ob = (float*)out + (long)e0 * NC;
        int nU4 = nU >> 2;
        float4* ob4 = (float4*)ob;
        const float4* sb4 = (const float4*)sh;
        for (int u = tid; u < nU4; u += 256) ob4[u] = sb4[u];
        for (int w = (nU4 << 2) + tid; w < nU; w += 256) ob[w] = sh[w];
    }
}

extern "C" void kernel_launch(void* const* d_in, const int* in_sizes, int n_in,
                              void* d_out, int out_size, void* d_ws, size_t ws_size,
                              hipStream_t stream) {
    const int* src = (const int*)d_in[0];
    const int* dst = (const int*)d_in[1];
    const void* nfeats = d_in[2];
    // d_in[3] = efeats, unused
    const void* W1  = d_in[4];
    const void* al1 = d_in[5];
    const void* ar1 = d_in[6];
    const void* b1  = d_in[7];
    const void* W2  = d_in[8];
    const void* al2 = d_in[9];
    const void* ar2 = d_in[10];
    const void* b2  = d_in[11];
    const void* Wp  = d_in[12];
    const void* bp  = d_in[13];

    const int E = in_sizes[0];
    const int N = in_sizes[2] / KIN;

    // workspace layout (256B aligned)
    size_t o = 0;
    auto alloc = [&](size_t bytes) { size_t r = o; o = (o + bytes + 255) & ~(size_t)255; return r; };
    char* ws = (char*)d_ws;
    int*   flag = (int*)  (ws + alloc(4));
    int*   deg  = (int*)  (ws + alloc((size_t)N * 4));
    int*   off  = (int*)  (ws + alloc((size_t)(N + 1) * 4));
    int*   cur  = (int*)  (ws + alloc((size_t)N * 4));
    int*   bsum = (int*)  (ws + alloc(64 * 4));
    int*   csr  = (int*)  (ws + alloc((size_t)E * 4));
    unsigned short* xb  = (unsigned short*)(ws + alloc((size_t)N * KIN * 2));
    unsigned short* fb  = (unsigned short*)(ws + alloc((size_t)N * HD * 2));
    unsigned short* hb  = (unsigned short*)(ws + alloc((size_t)N * HD * 2));
    unsigned short* Bp1 = (unsigned short*)(ws + alloc((size_t)12 * 4 * 512 * 2));
    unsigned short* Bp2 = (unsigned short*)(ws + alloc((size_t)12 * 6 * 512 * 2));
    unsigned short* BpPQ= (unsigned short*)(ws + alloc((size_t)2 * 6 * 512 * 2));
    float* el4  = (float*)(ws + alloc((size_t)N * 16));
    float* er4  = (float*)(ws + alloc((size_t)N * 16));
    float* PQ   = (float*)(ws + alloc((size_t)N * 2 * NC * 4));
    (void)ws_size; (void)n_in; (void)out_size;

    const int TB = 256;
    long nx = (long)N * KIN;
    int gE   = (E + TB - 1) / TB;
    int gAgg = (N + 3) / 4;
    int rowTiles = (N + 15) / 16;
    int gMM  = (rowTiles + 3) / 4;
    int nb   = (N + 1023) / 1024;

    // fused prep: probe + zero(deg) + cvt(xb, fp32 only) + all B-packs
    int bZ = (N + TB - 1) / TB;
    int bC = (int)((nx + TB - 1) / TB);
    int bP = (12 * 4 * 512 + 12 * 6 * 512 + 2 * 6 * 512 + TB - 1) / TB;
    k_prep<<<bZ + bC + bP, TB, 0, stream>>>(nfeats, W1, W2, Wp, xb, deg,
                                            Bp1, Bp2, BpPQ, N, nx, bZ, bC, flag);

    // CSR build (dst-indexed), hierarchical scan
    k_hist<<<gE, TB, 0, stream>>>(dst, E, deg);
    k_scan1<<<nb, 1024, 0, stream>>>(deg, N, off, bsum);
    k_scan2<<<1, 64, 0, stream>>>(bsum, nb, off, N);
    k_scan3<<<nb, 1024, 0, stream>>>(off, bsum, N, cur);
    k_fill<<<gE, TB, 0, stream>>>(src, dst, E, cur, csr);

    // layer 1: fused gemm+el/er, then softmax-aggregate
    k_mm<12, 4, 1><<<gMM, TB, 0, stream>>>(nfeats, xb, Bp1, fb, al1, ar1, el4, er4, N, HD, flag);
    k_agg<<<gAgg, TB, 0, stream>>>((const unsigned int*)fb, (const float4*)el4, er4,
                                   off, csr, b1, (unsigned int*)hb, N, flag);

    // layer 2
    k_mm<12, 6, 1><<<gMM, TB, 0, stream>>>(hb, hb, Bp2, fb, al2, ar2, el4, er4, N, HD, flag);
    k_agg<<<gAgg, TB, 0, stream>>>((const unsigned int*)fb, (const float4*)el4, er4,
                                   off, csr, b2, (unsigned int*)hb, N, flag);

    // predictor
    k_mmpq<<<gMM, TB, 0, stream>>>(hb, BpPQ, PQ, N);
    k_score<<<gE, TB, 0, stream>>>(src, dst, PQ, bp, d_out, E, flag);
}

// Round 8
// 398.363 us; speedup vs baseline: 1.2482x; 1.1078x over previous
//
#include <hip/hip_runtime.h>
#include <cstdint>

// GAT: N=50000 nodes, E=800000 edges, 128 -> 3 heads x 64, 2 layers, 10 classes
constexpr int KIN = 128;   // NDIM_IN
constexpr int HD  = 192;   // H * NDIM_OUT
constexpr int NC  = 10;    // CLASS_NUM
#define NEG_SLOPE 0.2f

typedef __attribute__((ext_vector_type(8))) short bf16x8;
typedef __attribute__((ext_vector_type(4))) float f32x4;

__device__ __forceinline__ float b2f(unsigned short u) {
    union { unsigned int i; float f; } x; x.i = ((unsigned int)u) << 16; return x.f;
}
__device__ __forceinline__ float b2f_lo(unsigned int u) {
    union { unsigned int i; float f; } x; x.i = u << 16; return x.f;
}
__device__ __forceinline__ float b2f_hi(unsigned int u) {
    union { unsigned int i; float f; } x; x.i = u & 0xffff0000u; return x.f;
}
__device__ __forceinline__ unsigned short f2b(float f) {
    union { float f; unsigned int i; } x; x.f = f;
    unsigned int r = x.i + 0x7FFFu + ((x.i >> 16) & 1u);   // RNE
    return (unsigned short)(r >> 16);
}
__device__ __forceinline__ float gload(const void* p, long i, int isbf) {
    return isbf ? b2f(((const unsigned short*)p)[i]) : ((const float*)p)[i];
}
__device__ __forceinline__ float lrelu(float v) { return v > 0.f ? v : NEG_SLOPE * v; }

// ================= fused prep: probe + zero(deg) + cvt(xb) + 4x pack =================
__global__ void k_prep(const void* __restrict__ nfeats, const void* __restrict__ W1,
                       const void* __restrict__ W2, const void* __restrict__ Wp,
                       unsigned short* __restrict__ xb, int* __restrict__ deg,
                       unsigned short* __restrict__ Bp1, unsigned short* __restrict__ Bp2,
                       unsigned short* __restrict__ BpPQ, int N, long nx,
                       int bZ, int bC, int* __restrict__ flag) {
    __shared__ int shIsb;
    if (threadIdx.x == 0) {
        const unsigned short* u = (const unsigned short*)W1;
        float mx = 0.f;
        for (int i = 0; i < 64; ++i) {
            float v = fabsf(b2f(u[i]));
            if (!(v < 1e30f)) v = 1e30f;
            mx = fmaxf(mx, v);
        }
        shIsb = (mx < 1e4f) ? 1 : 0;
        if (blockIdx.x == 0) *flag = shIsb;
    }
    __syncthreads();
    int isb = shIsb;
    int b = blockIdx.x, tid = threadIdx.x;
    if (b < bZ) { int i = b * 256 + tid; if (i < N) deg[i] = 0; return; }
    b -= bZ;
    if (b < bC) {
        if (isb) return;                    // bf16 input: k_mm reads nfeats directly
        long i = (long)b * 256 + tid;
        if (i < nx) xb[i] = f2b(gload(nfeats, i, isb));
        return;
    }
    b -= bC;
    int t = b * 256 + tid;
    const int s1 = 12 * 4 * 512, s2 = s1 + 12 * 6 * 512, s3 = s2 + 6 * 512, s4 = s3 + 6 * 512;
    const void* W; unsigned short* Bp; int K, Creal, KS; long rowOff; int tt;
    if (t < s1)      { W = W1; Bp = Bp1;            K = KIN; Creal = HD; KS = 4; rowOff = 0;  tt = t; }
    else if (t < s2) { W = W2; Bp = Bp2;            K = HD;  Creal = HD; KS = 6; rowOff = 0;  tt = t - s1; }
    else if (t < s3) { W = Wp; Bp = BpPQ;           K = HD;  Creal = NC; KS = 6; rowOff = 0;  tt = t - s2; }
    else if (t < s4) { W = Wp; Bp = BpPQ + 6 * 512; K = HD;  Creal = NC; KS = 6; rowOff = HD; tt = t - s3; }
    else return;
    int j = tt & 7, lane = (tt >> 3) & 63, ks = (tt >> 9) % KS, ct = tt / (KS * 512);
    int k = ks * 32 + ((lane >> 4) << 3) + j;
    int c = ct * 16 + (lane & 15);
    float v = 0.f;
    if (k < K && c < Creal) v = gload(W, (rowOff + k) * (long)Creal + c, isb);
    Bp[tt] = f2b(v);
}

// ---- MFMA GEMM + fused el/er epilogue. One wave = 16 rows x CT col-tiles.
template<int CT, int KS, int ELR>
__global__ void k_mm(const void* __restrict__ Ain, const unsigned short* __restrict__ xbA,
                     const unsigned short* __restrict__ Bp,
                     unsigned short* __restrict__ fb, const void* __restrict__ al,
                     const void* __restrict__ ar, float* __restrict__ el4,
                     float* __restrict__ er4, int M, int Cout, const int* __restrict__ flag) {
    int wid = threadIdx.x >> 6, lane = threadIdx.x & 63;
    int rt = blockIdx.x * 4 + wid;
    if (rt * 16 >= M) return;
    int isb = *flag;
    const unsigned short* A = isb ? (const unsigned short*)Ain : xbA;
    const int K = KS * 32;
    int mrow = rt * 16 + (lane & 15);
    int kq = (lane >> 4) << 3;
    f32x4 acc[CT];
#pragma unroll
    for (int ct = 0; ct < CT; ++ct) acc[ct] = (f32x4){0.f, 0.f, 0.f, 0.f};
    const unsigned short* arow = A + (long)mrow * K + kq;
    const bf16x8* bp = (const bf16x8*)Bp;
#pragma unroll
    for (int ks = 0; ks < KS; ++ks) {
        bf16x8 a = *(const bf16x8*)(arow + ks * 32);
#pragma unroll
        for (int ct = 0; ct < CT; ++ct) {
            bf16x8 b = bp[(ct * KS + ks) * 64 + lane];
            acc[ct] = __builtin_amdgcn_mfma_f32_16x16x32_bf16(a, b, acc[ct], 0, 0, 0);
        }
    }
    int quad = lane >> 4, c0 = lane & 15;
    int rbase = rt * 16 + quad * 4;
#pragma unroll
    for (int ct = 0; ct < CT; ++ct)
#pragma unroll
        for (int r = 0; r < 4; ++r)
            fb[(long)(rbase + r) * Cout + ct * 16 + c0] = f2b(acc[ct][r]);
    if (ELR) {
        float pl[3][4], pr[3][4];
#pragma unroll
        for (int h = 0; h < 3; ++h)
#pragma unroll
            for (int r = 0; r < 4; ++r) { pl[h][r] = 0.f; pr[h][r] = 0.f; }
#pragma unroll
        for (int ct = 0; ct < CT; ++ct) {
            int h = ct >> 2;
            float wl = gload(al, ct * 16 + c0, isb);
            float wr = gload(ar, ct * 16 + c0, isb);
#pragma unroll
            for (int r = 0; r < 4; ++r) {
                pl[h][r] += acc[ct][r] * wl;
                pr[h][r] += acc[ct][r] * wr;
            }
        }
#pragma unroll
        for (int d = 1; d < 16; d <<= 1)
#pragma unroll
            for (int h = 0; h < 3; ++h)
#pragma unroll
                for (int r = 0; r < 4; ++r) {
                    pl[h][r] += __shfl_xor(pl[h][r], d);
                    pr[h][r] += __shfl_xor(pr[h][r], d);
                }
        if (c0 == 0) {
#pragma unroll
            for (int r = 0; r < 4; ++r)
#pragma unroll
                for (int h = 0; h < 3; ++h) {
                    el4[(long)(rbase + r) * 4 + h] = pl[h][r];
                    er4[(long)(rbase + r) * 4 + h] = pr[h][r];
                }
        }
    }
}

// ---- fused P/Q gemm -> bf16 tables Pb/Qb, rows padded to 16 ushorts (32 B) ----
__global__ void k_mmpq(const unsigned short* __restrict__ A, const unsigned short* __restrict__ Bp,
                       unsigned short* __restrict__ Pb, unsigned short* __restrict__ Qb, int M) {
    constexpr int CT = 2, KS = 6;
    int wid = threadIdx.x >> 6, lane = threadIdx.x & 63;
    int rt = blockIdx.x * 4 + wid;
    if (rt * 16 >= M) return;
    const int K = KS * 32;
    int mrow = rt * 16 + (lane & 15);
    int kq = (lane >> 4) << 3;
    f32x4 acc[CT];
#pragma unroll
    for (int ct = 0; ct < CT; ++ct) acc[ct] = (f32x4){0.f, 0.f, 0.f, 0.f};
    const unsigned short* arow = A + (long)mrow * K + kq;
    const bf16x8* bp = (const bf16x8*)Bp;
#pragma unroll
    for (int ks = 0; ks < KS; ++ks) {
        bf16x8 a = *(const bf16x8*)(arow + ks * 32);
#pragma unroll
        for (int ct = 0; ct < CT; ++ct) {
            bf16x8 b = bp[(ct * KS + ks) * 64 + lane];
            acc[ct] = __builtin_amdgcn_mfma_f32_16x16x32_bf16(a, b, acc[ct], 0, 0, 0);
        }
    }
    int quad = lane >> 4, c0 = lane & 15;
    int rbase = rt * 16 + quad * 4;
    if (c0 < NC) {
#pragma unroll
        for (int r = 0; r < 4; ++r) {
            Pb[(long)(rbase + r) * 16 + c0] = f2b(acc[0][r]);
            Qb[(long)(rbase + r) * 16 + c0] = f2b(acc[1][r]);
        }
    }
}

// ---------------- CSR build ----------------
__global__ void k_hist(const int* __restrict__ dst, int E, int* __restrict__ deg) {
    int i = blockIdx.x * blockDim.x + threadIdx.x;
    if (i < E) atomicAdd(&deg[dst[i]], 1);
}

__global__ void k_scan1(const int* __restrict__ deg, int n, int* __restrict__ off,
                        int* __restrict__ bsum) {
    __shared__ int sh[1024];
    int tid = threadIdx.x, i = blockIdx.x * 1024 + tid;
    int v = (i < n) ? deg[i] : 0;
    sh[tid] = v;
    __syncthreads();
    for (int s = 1; s < 1024; s <<= 1) {
        int t = (tid >= s) ? sh[tid - s] : 0;
        __syncthreads();
        sh[tid] += t;
        __syncthreads();
    }
    if (i < n) off[i] = sh[tid] - v;
    if (tid == 1023) bsum[blockIdx.x] = sh[tid];
}

__global__ void k_scan2(int* __restrict__ bsum, int nb, int* __restrict__ off, int n) {
    int tid = threadIdx.x;
    int v = (tid < nb) ? bsum[tid] : 0;
    int incl = v;
    for (int s = 1; s < 64; s <<= 1) {
        int t = __shfl_up(incl, s);
        if (tid >= s) incl += t;
    }
    if (tid < nb) bsum[tid] = incl - v;
    if (tid == 63) off[n] = incl;
}

__global__ void k_scan3(int* __restrict__ off, const int* __restrict__ bsum, int n,
                        int* __restrict__ cur) {
    int i = blockIdx.x * 1024 + threadIdx.x;
    if (i < n) {
        int v = off[i] + bsum[blockIdx.x];
        off[i] = v;
        cur[i] = v;
    }
}

__global__ void k_fill(const int* __restrict__ src, const int* __restrict__ dst, int E,
                       int* __restrict__ cur, int* __restrict__ csr) {
    int i = blockIdx.x * blockDim.x + threadIdx.x;
    if (i < E) {
        int p = atomicAdd(&cur[dst[i]], 1);
        csr[p] = src[i];
    }
}

// ---- softmax + aggregation, one wave per node; 48-lane uint2 gather ----
__global__ void k_agg(const unsigned int* __restrict__ fbu, const float4* __restrict__ el4,
                      const float* __restrict__ er4, const int* __restrict__ off,
                      const int* __restrict__ csr, const void* __restrict__ bias,
                      unsigned int* __restrict__ outu, int Nn, const int* __restrict__ flag) {
    __shared__ float4 shW[4][64];
    int lane = threadIdx.x & 63;
    int wv = threadIdx.x >> 6;
    int n = blockIdx.x * 4 + wv;
    if (n >= Nn) return;
    int isb = *flag;
    int s0 = off[n], s1 = off[n + 1];
    int deg = s1 - s0;
    float er0 = er4[n * 4 + 0], er1 = er4[n * 4 + 1], er2 = er4[n * 4 + 2];
    int hsel = lane >> 4;                       // 0,1,2 for lanes<48
    float a0 = 0.f, a1 = 0.f, a2 = 0.f, a3 = 0.f;

    if (deg <= 64) {
        bool on = lane < deg;
        int sIdx = on ? csr[s0 + lane] : 0;
        float4 el = el4[sIdx];
        float t0 = on ? lrelu(el.x + er0) : -1e30f;
        float t1 = on ? lrelu(el.y + er1) : -1e30f;
        float t2 = on ? lrelu(el.z + er2) : -1e30f;
        float m0 = t0, m1 = t1, m2 = t2;
        for (int d = 1; d < 64; d <<= 1) {
            m0 = fmaxf(m0, __shfl_xor(m0, d));
            m1 = fmaxf(m1, __shfl_xor(m1, d));
            m2 = fmaxf(m2, __shfl_xor(m2, d));
        }
        float w0 = on ? __expf(t0 - m0) : 0.f;
        float w1 = on ? __expf(t1 - m1) : 0.f;
        float w2 = on ? __expf(t2 - m2) : 0.f;
        float d0 = w0, d1 = w1, d2 = w2;
        for (int d = 1; d < 64; d <<= 1) {
            d0 += __shfl_xor(d0, d);
            d1 += __shfl_xor(d1, d);
            d2 += __shfl_xor(d2, d);
        }
        w0 *= 1.f / d0; w1 *= 1.f / d1; w2 *= 1.f / d2;
        shW[wv][lane] = make_float4(__int_as_float(sIdx), w0, w1, w2);
        if (lane < 48) {
            const float4* wr = shW[wv];
            long lb = 2 * lane;
            int j = 0;
            for (; j + 4 <= deg; j += 4) {
                float4 r0 = wr[j], r1 = wr[j + 1], r2 = wr[j + 2], r3 = wr[j + 3];
                uint2 u0 = *(const uint2*)(fbu + (long)__float_as_int(r0.x) * 96 + lb);
                uint2 u1 = *(const uint2*)(fbu + (long)__float_as_int(r1.x) * 96 + lb);
                uint2 u2 = *(const uint2*)(fbu + (long)__float_as_int(r2.x) * 96 + lb);
                uint2 u3 = *(const uint2*)(fbu + (long)__float_as_int(r3.x) * 96 + lb);
                float q0 = hsel == 0 ? r0.y : (hsel == 1 ? r0.z : r0.w);
                float q1 = hsel == 0 ? r1.y : (hsel == 1 ? r1.z : r1.w);
                float q2 = hsel == 0 ? r2.y : (hsel == 1 ? r2.z : r2.w);
                float q3 = hsel == 0 ? r3.y : (hsel == 1 ? r3.z : r3.w);
                a0 += q0 * b2f_lo(u0.x); a1 += q0 * b2f_hi(u0.x);
                a2 += q0 * b2f_lo(u0.y); a3 += q0 * b2f_hi(u0.y);
                a0 += q1 * b2f_lo(u1.x); a1 += q1 * b2f_hi(u1.x);
                a2 += q1 * b2f_lo(u1.y); a3 += q1 * b2f_hi(u1.y);
                a0 += q2 * b2f_lo(u2.x); a1 += q2 * b2f_hi(u2.x);
                a2 += q2 * b2f_lo(u2.y); a3 += q2 * b2f_hi(u2.y);
                a0 += q3 * b2f_lo(u3.x); a1 += q3 * b2f_hi(u3.x);
                a2 += q3 * b2f_lo(u3.y); a3 += q3 * b2f_hi(u3.y);
            }
            for (; j < deg; ++j) {
                float4 r0 = wr[j];
                uint2 u0 = *(const uint2*)(fbu + (long)__float_as_int(r0.x) * 96 + lb);
                float q0 = hsel == 0 ? r0.y : (hsel == 1 ? r0.z : r0.w);
                a0 += q0 * b2f_lo(u0.x); a1 += q0 * b2f_hi(u0.x);
                a2 += q0 * b2f_lo(u0.y); a3 += q0 * b2f_hi(u0.y);
            }
        }
    } else {
        float m0 = -1e30f, m1 = -1e30f, m2 = -1e30f;
        for (int e = s0 + lane; e < s1; e += 64) {
            float4 el = el4[csr[e]];
            m0 = fmaxf(m0, lrelu(el.x + er0));
            m1 = fmaxf(m1, lrelu(el.y + er1));
            m2 = fmaxf(m2, lrelu(el.z + er2));
        }
        for (int d = 1; d < 64; d <<= 1) {
            m0 = fmaxf(m0, __shfl_xor(m0, d));
            m1 = fmaxf(m1, __shfl_xor(m1, d));
            m2 = fmaxf(m2, __shfl_xor(m2, d));
        }
        float d0 = 0.f, d1 = 0.f, d2 = 0.f;
        for (int e = s0 + lane; e < s1; e += 64) {
            float4 el = el4[csr[e]];
            d0 += __expf(lrelu(el.x + er0) - m0);
            d1 += __expf(lrelu(el.y + er1) - m1);
            d2 += __expf(lrelu(el.z + er2) - m2);
        }
        for (int d = 1; d < 64; d <<= 1) {
            d0 += __shfl_xor(d0, d);
            d1 += __shfl_xor(d1, d);
            d2 += __shfl_xor(d2, d);
        }
        if (lane < 48) {
            float mh  = hsel == 0 ? m0 : (hsel == 1 ? m1 : m2);
            float dh  = hsel == 0 ? d0 : (hsel == 1 ? d1 : d2);
            float erh = hsel == 0 ? er0 : (hsel == 1 ? er1 : er2);
            float idh = 1.f / dh;
            long lb = 2 * lane;
            for (int e = s0; e < s1; ++e) {
                int s = csr[e];
                float4 el = el4[s];
                float eh = hsel == 0 ? el.x : (hsel == 1 ? el.y : el.z);
                float w = __expf(lrelu(eh + erh) - mh) * idh;
                uint2 u = *(const uint2*)(fbu + (long)s * 96 + lb);
                a0 += w * b2f_lo(u.x); a1 += w * b2f_hi(u.x);
                a2 += w * b2f_lo(u.y); a3 += w * b2f_hi(u.y);
            }
        }
    }
    if (lane < 48) {
        int c = 4 * lane;
        a0 = fmaxf(a0 + gload(bias, c,     isb), 0.f);
        a1 = fmaxf(a1 + gload(bias, c + 1, isb), 0.f);
        a2 = fmaxf(a2 + gload(bias, c + 2, isb), 0.f);
        a3 = fmaxf(a3 + gload(bias, c + 3, isb), 0.f);
        uint2 o;
        o.x = (unsigned)f2b(a0) | ((unsigned)f2b(a1) << 16);
        o.y = (unsigned)f2b(a2) | ((unsigned)f2b(a3) << 16);
        *(uint2*)(outu + (long)n * 96 + 2 * lane) = o;
    }
}

// ---- per-edge score: 2 edges/thread, bf16 P/Q gather (uint4+uint), LDS-staged writes ----
__global__ void k_score(const int* __restrict__ src, const int* __restrict__ dst,
                        const unsigned int* __restrict__ Pu, const unsigned int* __restrict__ Qu,
                        const void* __restrict__ bp, void* __restrict__ out,
                        int E, const int* __restrict__ flag) {
    __shared__ float sh[512 * NC];            // 20 KB
    int tid = threadIdx.x;
    int e0 = blockIdx.x * 512;
    int isb = *flag;
    float bb[NC];
#pragma unroll
    for (int c = 0; c < NC; ++c) bb[c] = gload(bp, c, isb);

    float v[2][NC];
#pragma unroll
    for (int k = 0; k < 2; ++k) {
        int e = e0 + tid + k * 256;
        if (e < E) {
            const uint4* p4 = (const uint4*)(Pu + (long)src[e] * 8);
            const uint4* q4 = (const uint4*)(Qu + (long)dst[e] * 8);
            uint4 pa = p4[0]; unsigned int pb_ = Pu[(long)src[e] * 8 + 4];
            uint4 qa = q4[0]; unsigned int qb_ = Qu[(long)dst[e] * 8 + 4];
            v[k][0] = b2f_lo(pa.x) + b2f_lo(qa.x) + bb[0];
            v[k][1] = b2f_hi(pa.x) + b2f_hi(qa.x) + bb[1];
            v[k][2] = b2f_lo(pa.y) + b2f_lo(qa.y) + bb[2];
            v[k][3] = b2f_hi(pa.y) + b2f_hi(qa.y) + bb[3];
            v[k][4] = b2f_lo(pa.z) + b2f_lo(qa.z) + bb[4];
            v[k][5] = b2f_hi(pa.z) + b2f_hi(qa.z) + bb[5];
            v[k][6] = b2f_lo(pa.w) + b2f_lo(qa.w) + bb[6];
            v[k][7] = b2f_hi(pa.w) + b2f_hi(qa.w) + bb[7];
            v[k][8] = b2f_lo(pb_)  + b2f_lo(qb_)  + bb[8];
            v[k][9] = b2f_hi(pb_)  + b2f_hi(qb_)  + bb[9];
        }
    }
    int nE = min(512, E - e0);
    if (isb) {
        unsigned int* shu = (unsigned int*)sh;
#pragma unroll
        for (int k = 0; k < 2; ++k) {
            int le = tid + k * 256;
            if (e0 + le < E) {
#pragma unroll
                for (int c = 0; c < NC / 2; ++c)
                    shu[le * (NC / 2) + c] =
                        (unsigned)f2b(v[k][2 * c]) | ((unsigned)f2b(v[k][2 * c + 1]) << 16);
            }
        }
        __syncthreads();
        int nU = nE * (NC / 2);
        unsigned int* ob = (unsigned int*)((unsigned short*)out + (long)e0 * NC);
        int nU4 = nU >> 2;
        uint4* ob4 = (uint4*)ob;
        const uint4* sb4 = (const uint4*)shu;
        for (int u = tid; u < nU4; u += 256) ob4[u] = sb4[u];
        for (int w = (nU4 << 2) + tid; w < nU; w += 256) ob[w] = shu[w];
    } else {
#pragma unroll
        for (int k = 0; k < 2; ++k) {
            int le = tid + k * 256;
            if (e0 + le < E) {
#pragma unroll
                for (int c = 0; c < NC; ++c) sh[le * NC + c] = v[k][c];
            }
        }
        __syncthreads();
        int nU = nE * NC;
        float* ob = (float*)out + (long)e0 * NC;
        int nU4 = nU >> 2;
        float4* ob4 = (float4*)ob;
        const float4* sb4 = (const float4*)sh;
        for (int u = tid; u < nU4; u += 256) ob4[u] = sb4[u];
        for (int w = (nU4 << 2) + tid; w < nU; w += 256) ob[w] = sh[w];
    }
}

extern "C" void kernel_launch(void* const* d_in, const int* in_sizes, int n_in,
                              void* d_out, int out_size, void* d_ws, size_t ws_size,
                              hipStream_t stream) {
    const int* src = (const int*)d_in[0];
    const int* dst = (const int*)d_in[1];
    const void* nfeats = d_in[2];
    // d_in[3] = efeats, unused
    const void* W1  = d_in[4];
    const void* al1 = d_in[5];
    const void* ar1 = d_in[6];
    const void* b1  = d_in[7];
    const void* W2  = d_in[8];
    const void* al2 = d_in[9];
    const void* ar2 = d_in[10];
    const void* b2  = d_in[11];
    const void* Wp  = d_in[12];
    const void* bp  = d_in[13];

    const int E = in_sizes[0];
    const int N = in_sizes[2] / KIN;

    // workspace layout (256B aligned)
    size_t o = 0;
    auto alloc = [&](size_t bytes) { size_t r = o; o = (o + bytes + 255) & ~(size_t)255; return r; };
    char* ws = (char*)d_ws;
    int*   flag = (int*)  (ws + alloc(4));
    int*   deg  = (int*)  (ws + alloc((size_t)N * 4));
    int*   off  = (int*)  (ws + alloc((size_t)(N + 1) * 4));
    int*   cur  = (int*)  (ws + alloc((size_t)N * 4));
    int*   bsum = (int*)  (ws + alloc(64 * 4));
    int*   csr  = (int*)  (ws + alloc((size_t)E * 4));
    unsigned short* xb  = (unsigned short*)(ws + alloc((size_t)N * KIN * 2));
    unsigned short* fb  = (unsigned short*)(ws + alloc((size_t)N * HD * 2));
    unsigned short* hb  = (unsigned short*)(ws + alloc((size_t)N * HD * 2));
    unsigned short* Bp1 = (unsigned short*)(ws + alloc((size_t)12 * 4 * 512 * 2));
    unsigned short* Bp2 = (unsigned short*)(ws + alloc((size_t)12 * 6 * 512 * 2));
    unsigned short* BpPQ= (unsigned short*)(ws + alloc((size_t)2 * 6 * 512 * 2));
    float* el4  = (float*)(ws + alloc((size_t)N * 16));
    float* er4  = (float*)(ws + alloc((size_t)N * 16));
    unsigned short* Pb = (unsigned short*)(ws + alloc((size_t)N * 16 * 2));
    unsigned short* Qb = (unsigned short*)(ws + alloc((size_t)N * 16 * 2));
    (void)ws_size; (void)n_in; (void)out_size;

    const int TB = 256;
    long nx = (long)N * KIN;
    int gE   = (E + TB - 1) / TB;
    int gSc  = (E + 511) / 512;
    int gAgg = (N + 3) / 4;
    int rowTiles = (N + 15) / 16;
    int gMM  = (rowTiles + 3) / 4;
    int nb   = (N + 1023) / 1024;

    // fused prep: probe + zero(deg) + cvt(xb, fp32 only) + all B-packs
    int bZ = (N + TB - 1) / TB;
    int bC = (int)((nx + TB - 1) / TB);
    int bP = (12 * 4 * 512 + 12 * 6 * 512 + 2 * 6 * 512 + TB - 1) / TB;
    k_prep<<<bZ + bC + bP, TB, 0, stream>>>(nfeats, W1, W2, Wp, xb, deg,
                                            Bp1, Bp2, BpPQ, N, nx, bZ, bC, flag);

    // CSR build (dst-indexed), hierarchical scan
    k_hist<<<gE, TB, 0, stream>>>(dst, E, deg);
    k_scan1<<<nb, 1024, 0, stream>>>(deg, N, off, bsum);
    k_scan2<<<1, 64, 0, stream>>>(bsum, nb, off, N);
    k_scan3<<<nb, 1024, 0, stream>>>(off, bsum, N, cur);
    k_fill<<<gE, TB, 0, stream>>>(src, dst, E, cur, csr);

    // layer 1: fused gemm+el/er, then softmax-aggregate
    k_mm<12, 4, 1><<<gMM, TB, 0, stream>>>(nfeats, xb, Bp1, fb, al1, ar1, el4, er4, N, HD, flag);
    k_agg<<<gAgg, TB, 0, stream>>>((const unsigned int*)fb, (const float4*)el4, er4,
                                   off, csr, b1, (unsigned int*)hb, N, flag);

    // layer 2
    k_mm<12, 6, 1><<<gMM, TB, 0, stream>>>(hb, hb, Bp2, fb, al2, ar2, el4, er4, N, HD, flag);
    k_agg<<<gAgg, TB, 0, stream>>>((const unsigned int*)fb, (const float4*)el4, er4,
                                   off, csr, b2, (unsigned int*)hb, N, flag);

    // predictor
    k_mmpq<<<gMM, TB, 0, stream>>>(hb, BpPQ, Pb, Qb, N);
    k_score<<<gSc, TB, 0, stream>>>(src, dst, (const unsigned int*)Pb, (const unsigned int*)Qb,
                                    bp, d_out, E, flag);
}